// Round 1
// baseline (132.847 us; speedup 1.0000x reference)
//
#include <hip/hip_runtime.h>

// DecoupledSOLOHead: SOLO mask decode + Matrix NMS (gaussian), MI355X/gfx950.
//
// R9 vs R8 (127.1 us): class-local NMS fusion.
//   decay_coef[j] = min(1, min_{i<j same class} exp(sigma*(comp2[i]-iou2[i,j])))
//   (cross-class / lower-tri terms are exp(sigma*comp2[i]) >= 1, and comp2[0]=0
//   pins the clamp at 1) -> Matrix NMS decomposes per class. One block per
//   class computes pair IoUs, comp^2, decay, scores AND writes out[] directly.
//   Eliminates: pair_iou kernel (500 blocks: per-block label re-reads, d2col
//   column zeroing = 1MB poison-defensive writes, redundant row preloads),
//   decay kernel, d2col (1MB W + 1MB R), comp2/scores round trips, one
//   dependency gap. 4 dispatches -> 3.
//   maskgen / transpose unchanged from R8 (proven, HBM-/latency-optimal).

#define N_DET 500
#define HW    (200 * 304)        // 60800
#define TILE  64
#define NT    (HW / TILE)        // 950 tiles, exact
#define PSTR  512                // det stride in tile-major arrays
#define DSTR  950                // tile stride in det-major arrays
#define NW2   (NT / 2)           // 475 ulonglong2 granules per det row
#define NCLS  80
#define MM    64                 // max members/class (binomial(500,1/80): ~6 avg, ~15 max)
#define MASK_THR 0.005f
#define SIGMA 2.0f

// ---------------- Kernel A: pixel-tiled broadcast decode + bit-pack ------------
__global__ __launch_bounds__(512) void maskgen_kernel(
    const float* __restrict__ seg_x, const float* __restrict__ seg_y,
    const int* __restrict__ x_inds, const int* __restrict__ y_inds,
    unsigned long long* __restrict__ packed_t,  // [NT][PSTR] tile-major
    float* __restrict__ part_sum)               // [NT][PSTR]
{
    __shared__ __align__(16) float sx[128 * 64];     // 32,768 B
    __shared__ __align__(16) float sy[128 * 64];     // 32,768 B
    const int t   = blockIdx.x;
    const int tid = threadIdx.x;
    const int base = t * TILE;

    // stage 128 rows x 64 px of each operand; b128 both sides, bank-balanced
    for (int e = tid; e < 128 * 16; e += 512) {
        const int r  = e >> 4;
        const int c4 = (e & 15) << 2;
        *(float4*)(sx + (r << 6) + c4) = *(const float4*)(seg_x + (size_t)r * HW + base + c4);
        *(float4*)(sy + (r << 6) + c4) = *(const float4*)(seg_y + (size_t)r * HW + base + c4);
    }
    __syncthreads();

    // thread = det; lane-rotated phase makes every b128 read conflict-free
    if (tid < N_DET) {
        const float4* __restrict__ rx4 = (const float4*)(sx + (x_inds[tid] << 6));
        const float4* __restrict__ ry4 = (const float4*)(sy + (y_inds[tid] << 6));
        float ssum = 0.0f;
        unsigned long long w = 0ull;
        #pragma unroll
        for (int k = 0; k < 16; ++k) {
            const int f = (k + tid) & 15;            // 8 lanes per bank-quad
            const float4 xv = rx4[f];
            const float4 yv = ry4[f];
            const float p0 = xv.x * yv.x, p1 = xv.y * yv.y,
                        p2 = xv.z * yv.z, p3 = xv.w * yv.w;
            const int b0 = p0 > MASK_THR, b1 = p1 > MASK_THR,
                      b2 = p2 > MASK_THR, b3 = p3 > MASK_THR;
            ssum += (b0 ? p0 : 0.0f) + (b1 ? p1 : 0.0f)
                  + (b2 ? p2 : 0.0f) + (b3 ? p3 : 0.0f);
            const unsigned int nib = (unsigned)(b0 | (b1 << 1) | (b2 << 2) | (b3 << 3));
            w |= (unsigned long long)nib << (f << 2);  // pixel-order bits
        }
        packed_t[(size_t)t * PSTR + tid] = w;          // coalesced
        part_sum[(size_t)t * PSTR + tid] = ssum;       // coalesced
    }
}

// ------- Kernel T: 64x64 LDS tile transpose -> det-major layouts ---------------
__global__ __launch_bounds__(512) void transpose_kernel(
    const unsigned long long* __restrict__ packed_t,  // [NT][PSTR]
    const float* __restrict__ part_sum,               // [NT][PSTR]
    unsigned long long* __restrict__ packed_d,        // [N_DET][DSTR]
    float* __restrict__ part_sumT)                    // [N_DET][DSTR]
{
    __shared__ unsigned long long tp[64 * 65];        // 33,280 B
    __shared__ float              ts[64 * 65];        // 16,640 B
    const int t0  = blockIdx.x * 64;                  // 15 x-tiles -> 960 (>=950)
    const int d0  = blockIdx.y * 64;                  // 8 y-tiles  -> 512
    const int tid = threadIdx.x;
    const int lane = tid & 63, wav = tid >> 6;        // 8 waves

    #pragma unroll
    for (int k = 0; k < 8; ++k) {
        const int r  = (k << 3) + wav;                // 0..63
        const int gt = t0 + r;
        unsigned long long v = 0ull; float s = 0.0f;
        if (gt < NT) {
            v = packed_t[(size_t)gt * PSTR + d0 + lane];   // 512 B coalesced
            s = part_sum[(size_t)gt * PSTR + d0 + lane];
        }
        tp[r * 65 + lane] = v;
        ts[r * 65 + lane] = s;
    }
    __syncthreads();
    const int gt = t0 + lane;
    #pragma unroll
    for (int k = 0; k < 8; ++k) {
        const int m = (k << 3) + wav;
        const int d = d0 + m;
        if (gt < NT && d < N_DET) {
            packed_d [(size_t)d * DSTR + gt] = tp[lane * 65 + m];  // coalesced
            part_sumT[(size_t)d * DSTR + gt] = ts[lane * 65 + m];
        }
    }
}

// ------- Kernel C: class-local fused NMS (scores + IoU + comp + decay + out) ---
__global__ __launch_bounds__(512) void class_nms_kernel(
    const unsigned long long* __restrict__ packed_d,   // [N_DET][DSTR]
    const float* __restrict__ part_sumT,               // [N_DET][DSTR]
    const int* __restrict__ labels,
    const float* __restrict__ cate_scores,
    float* __restrict__ out)                           // [N_DET]
{
    const int c    = blockIdx.x;                       // class id, 0..79
    const int tid  = threadIdx.x;
    const int lane = tid & 63, wav = tid >> 6;         // 8 waves

    __shared__ int   s_list[MM];                       // member det indices, ascending
    __shared__ int   s_wcnt[8];
    __shared__ float s_cnt[MM];                        // mask areas
    __shared__ float s_sc[MM];                         // cate * seg_score
    __shared__ float s_comp[MM];                       // comp_iou^2
    __shared__ float pm[MM * MM];                      // iou[mi][mj], mi<mj (16 KB)
    __shared__ int   s_m;

    // ---- ordered member discovery: ballot compaction (waves cover ascending idx)
    int flag = 0;
    if (tid < N_DET) flag = (labels[tid] == c);
    const unsigned long long bmask = __ballot(flag);
    if (lane == 0) s_wcnt[wav] = __popcll(bmask);
    __syncthreads();
    int pre = 0;
    for (int w2 = 0; w2 < wav; ++w2) pre += s_wcnt[w2];
    if (flag) {
        const int pos = pre + __popcll(bmask & ((1ull << lane) - 1ull));
        if (pos < MM) s_list[pos] = tid;
    }
    if (tid == 0) {
        int mm = 0;
        for (int w2 = 0; w2 < 8; ++w2) mm += s_wcnt[w2];
        s_m = (mm > MM) ? MM : mm;
    }
    __syncthreads();
    const int m = s_m;
    if (m == 0) return;                                // uniform exit

    // ---- per-member area + rescored score: one wave per member, coalesced rows
    for (int mi = wav; mi < m; mi += 8) {
        const int i = s_list[mi];
        const ulonglong2* __restrict__ pi2 = (const ulonglong2*)(packed_d + (size_t)i * DSTR);
        const float2*     __restrict__ ps2 = (const float2*)(part_sumT + (size_t)i * DSTR);
        int cnt = 0; float S = 0.0f;
        #pragma unroll
        for (int q = 0; q < 8; ++q) {
            const int w = lane + (q << 6);
            if (w < NW2) {
                const ulonglong2 a = pi2[w];
                cnt += __popcll(a.x) + __popcll(a.y);
                const float2 s2 = ps2[w];
                S += s2.x + s2.y;
            }
        }
        float fcnt = (float)cnt;
        #pragma unroll
        for (int off = 32; off; off >>= 1) {
            fcnt += __shfl_down(fcnt, off);
            S    += __shfl_down(S,    off);
        }
        if (lane == 0) {
            s_cnt[mi] = fcnt;
            s_sc[mi]  = cate_scores[i] * (S / fmaxf(fcnt, 1.0f));
        }
    }
    __syncthreads();

    // ---- all within-class pairs: one wave per pair, rows L2-hot (<=150 KB/class)
    const int npairs = m * (m - 1) / 2;
    for (int p = wav; p < npairs; p += 8) {
        int mj = 1;                                    // largest mj with mj(mj-1)/2 <= p
        while ((mj * (mj + 1)) / 2 <= p) ++mj;         // wave-uniform, m small
        const int mi = p - mj * (mj - 1) / 2;
        const int i = s_list[mi], j = s_list[mj];
        const ulonglong2* __restrict__ pi2 = (const ulonglong2*)(packed_d + (size_t)i * DSTR);
        const ulonglong2* __restrict__ pj2 = (const ulonglong2*)(packed_d + (size_t)j * DSTR);
        int inter = 0;
        #pragma unroll
        for (int q = 0; q < 8; ++q) {
            const int w = lane + (q << 6);
            if (w < NW2) {
                const ulonglong2 a = pi2[w];
                const ulonglong2 b = pj2[w];
                inter += __popcll(a.x & b.x) + __popcll(a.y & b.y);
            }
        }
        float fint = (float)inter;
        #pragma unroll
        for (int off = 32; off; off >>= 1) fint += __shfl_down(fint, off);
        if (lane == 0) {
            const float uni = s_cnt[mi] + s_cnt[mj] - fint;
            pm[mi * MM + mj] = fint / fmaxf(uni, 1e-6f);   // iou
        }
    }
    __syncthreads();

    // ---- comp^2 then decay + output: single wave, lane = member index
    if (wav == 0 && lane < m) {
        const int mj = lane;
        float cmax = 0.0f;
        for (int mi = 0; mi < mj; ++mi) cmax = fmaxf(cmax, pm[mi * MM + mj]);
        s_comp[mj] = cmax * cmax;
    }
    __syncthreads();
    if (wav == 0 && lane < m) {
        const int mj = lane;
        float e = 0.0f;                                // min(0, ...) — clamp at coef 1
        for (int mi = 0; mi < mj; ++mi) {
            const float d = pm[mi * MM + mj];
            e = fminf(e, s_comp[mi] - d * d);
        }
        out[s_list[mj]] = s_sc[mj] * expf(SIGMA * e);
    }
}

extern "C" void kernel_launch(void* const* d_in, const int* in_sizes, int n_in,
                              void* d_out, int out_size, void* d_ws, size_t ws_size,
                              hipStream_t stream) {
    const float* cate_scores = (const float*)d_in[0];
    const float* seg_x       = (const float*)d_in[1];
    const float* seg_y       = (const float*)d_in[2];
    const int*   labels      = (const int*)d_in[3];
    const int*   x_inds      = (const int*)d_in[4];
    const int*   y_inds      = (const int*)d_in[5];
    float* out = (float*)d_out;

    // workspace layout (16B-aligned); total ~11.54 MB
    char* ws = (char*)d_ws;
    unsigned long long* packed_t = (unsigned long long*)(ws + 0);        // 950*512*8 = 3,891,200
    float* part_sum  = (float*)(ws + 3891200);                           // 950*512*4 = 1,945,600
    unsigned long long* packed_d = (unsigned long long*)(ws + 5836800);  // 500*950*8 = 3,800,000
    float* part_sumT = (float*)(ws + 9636800);                           // 500*950*4 = 1,900,000

    maskgen_kernel  <<<NT, 512, 0, stream>>>(seg_x, seg_y, x_inds, y_inds,
                                             packed_t, part_sum);
    transpose_kernel<<<dim3(15, 8), 512, 0, stream>>>(packed_t, part_sum,
                                                      packed_d, part_sumT);
    class_nms_kernel<<<NCLS, 512, 0, stream>>>(packed_d, part_sumT, labels,
                                               cate_scores, out);
}

// Round 2
// 130.395 us; speedup vs baseline: 1.0188x; 1.0188x over previous
//
#include <hip/hip_runtime.h>

// DecoupledSOLOHead: SOLO mask decode + Matrix NMS (gaussian), MI355X/gfx950.
//
// R10 vs R9 (132.8 us): kill the transpose stage entirely.
//  - maskgen: each block owns GRP=4 consecutive 64-px tiles; loops the proven
//    64KB LDS broadcast-stage + rotated conflict-free gather 4x, accumulating
//    4 packed words/det in registers, then writes a 32B det-major chunk
//    (DSTR=952 pads rows to 7616B -> every chunk 32B-sector aligned, no write
//    amplification; tail tiles 950/951 auto-zeroed). packed_t/part_sum
//    tile-major round trip (5.8MB R + 3.5MB W) and the transpose dispatch +
//    its dependency gap are gone. 3 dispatches -> 2.
//  - part sums collapse 4:1 -> part4[d][238] (480KB), read scalar-coalesced.
//  - class_nms: 1024 threads (16 waves) halves stats/pair rounds for the
//    worst class (R9's 8-wave/80-block version was the likely regression vs
//    R8's 500-block pair_iou). Math identical to R9 (passed, absmax 0).

#define N_DET 500
#define HW    (200 * 304)        // 60800
#define TILE  64
#define NT    (HW / TILE)        // 950 tiles, exact
#define GRP   4                  // tiles per maskgen block
#define NG    238                // ceil(950/4) tile groups
#define DSTR  952                // padded det-major row stride (words; 7616B, 32B-aligned chunks)
#define NW2   (DSTR / 2)         // 476 ulonglong2 granules per det row
#define PS_STR 240               // part4 row stride (floats); slots [238,240) never read
#define NCLS  80
#define MM    64                 // max members/class (binomial(500,1/80): ~6 avg, ~15 max)
#define MASK_THR 0.005f
#define SIGMA 2.0f

// ---- Kernel A: 4-tile broadcast decode + bit-pack, det-major direct ----------
__global__ __launch_bounds__(512) void maskgen_kernel(
    const float* __restrict__ seg_x, const float* __restrict__ seg_y,
    const int* __restrict__ x_inds, const int* __restrict__ y_inds,
    unsigned long long* __restrict__ packed_d,  // [N_DET][DSTR]
    float* __restrict__ part4)                  // [N_DET][PS_STR]
{
    __shared__ __align__(16) float sx[128 * 64];     // 32,768 B
    __shared__ __align__(16) float sy[128 * 64];     // 32,768 B
    const int g   = blockIdx.x;
    const int tid = threadIdx.x;

    int xrow = 0, yrow = 0;
    if (tid < N_DET) { xrow = x_inds[tid] << 6; yrow = y_inds[tid] << 6; }

    unsigned long long wacc[GRP];
    float ssum = 0.0f;

    #pragma unroll
    for (int u = 0; u < GRP; ++u) {
        const int t = g * GRP + u;                   // block-uniform
        unsigned long long w = 0ull;
        if (t < NT) {                                // uniform branch, barriers legal
            const int base = t * TILE;
            __syncthreads();                         // LDS reuse guard (u>0)
            for (int e = tid; e < 128 * 16; e += 512) {
                const int r  = e >> 4;
                const int c4 = (e & 15) << 2;
                *(float4*)(sx + (r << 6) + c4) = *(const float4*)(seg_x + (size_t)r * HW + base + c4);
                *(float4*)(sy + (r << 6) + c4) = *(const float4*)(seg_y + (size_t)r * HW + base + c4);
            }
            __syncthreads();
            if (tid < N_DET) {
                const float4* __restrict__ rx4 = (const float4*)(sx + xrow);
                const float4* __restrict__ ry4 = (const float4*)(sy + yrow);
                #pragma unroll
                for (int k = 0; k < 16; ++k) {
                    const int f = (k + tid) & 15;    // 8 lanes per bank-quad
                    const float4 xv = rx4[f];
                    const float4 yv = ry4[f];
                    const float p0 = xv.x * yv.x, p1 = xv.y * yv.y,
                                p2 = xv.z * yv.z, p3 = xv.w * yv.w;
                    const int b0 = p0 > MASK_THR, b1 = p1 > MASK_THR,
                              b2 = p2 > MASK_THR, b3 = p3 > MASK_THR;
                    ssum += (b0 ? p0 : 0.0f) + (b1 ? p1 : 0.0f)
                          + (b2 ? p2 : 0.0f) + (b3 ? p3 : 0.0f);
                    const unsigned int nib = (unsigned)(b0 | (b1 << 1) | (b2 << 2) | (b3 << 3));
                    w |= (unsigned long long)nib << (f << 2);  // pixel-order bits
                }
            }
        }
        wacc[u] = w;                                 // tail tiles (>=950) stay 0
    }

    if (tid < N_DET) {
        unsigned long long* dst = packed_d + (size_t)tid * DSTR + g * GRP;
        ulonglong2 lo; lo.x = wacc[0]; lo.y = wacc[1];
        ulonglong2 hi; hi.x = wacc[2]; hi.y = wacc[3];
        *(ulonglong2*)(dst)     = lo;                // 32B sector-aligned chunk
        *(ulonglong2*)(dst + 2) = hi;
        part4[(size_t)tid * PS_STR + g] = ssum;
    }
}

// ------- Kernel B: class-local fused NMS (scores + IoU + comp + decay + out) ---
__global__ __launch_bounds__(1024) void class_nms_kernel(
    const unsigned long long* __restrict__ packed_d,   // [N_DET][DSTR]
    const float* __restrict__ part4,                   // [N_DET][PS_STR]
    const int* __restrict__ labels,
    const float* __restrict__ cate_scores,
    float* __restrict__ out)                           // [N_DET]
{
    const int c    = blockIdx.x;                       // class id, 0..79
    const int tid  = threadIdx.x;
    const int lane = tid & 63, wav = tid >> 6;         // 16 waves

    __shared__ int   s_list[MM];                       // member det indices, ascending
    __shared__ int   s_wcnt[16];
    __shared__ float s_cnt[MM];                        // mask areas
    __shared__ float s_sc[MM];                         // cate * seg_score
    __shared__ float s_comp[MM];                       // comp_iou^2
    __shared__ float pm[MM * MM];                      // iou[mi][mj], mi<mj (16 KB)
    __shared__ int   s_m;

    // ---- ordered member discovery: ballot compaction (waves cover ascending idx)
    int flag = 0;
    if (tid < N_DET) flag = (labels[tid] == c);
    const unsigned long long bmask = __ballot(flag);
    if (lane == 0) s_wcnt[wav] = __popcll(bmask);
    __syncthreads();
    int pre = 0;
    for (int w2 = 0; w2 < wav; ++w2) pre += s_wcnt[w2];
    if (flag) {
        const int pos = pre + __popcll(bmask & ((1ull << lane) - 1ull));
        if (pos < MM) s_list[pos] = tid;
    }
    if (tid == 0) {
        int mm = 0;
        for (int w2 = 0; w2 < 16; ++w2) mm += s_wcnt[w2];
        s_m = (mm > MM) ? MM : mm;
    }
    __syncthreads();
    const int m = s_m;
    if (m == 0) return;                                // uniform exit

    // ---- per-member area + rescored score: one wave per member, coalesced rows
    for (int mi = wav; mi < m; mi += 16) {
        const int i = s_list[mi];
        const ulonglong2* __restrict__ pi2 = (const ulonglong2*)(packed_d + (size_t)i * DSTR);
        const float*      __restrict__ ps  = part4 + (size_t)i * PS_STR;
        int cnt = 0;
        #pragma unroll
        for (int q = 0; q < 8; ++q) {
            const int w = lane + (q << 6);
            if (w < NW2) {
                const ulonglong2 a = pi2[w];
                cnt += __popcll(a.x) + __popcll(a.y);
            }
        }
        float S = 0.0f;
        #pragma unroll
        for (int q = 0; q < 4; ++q) {
            const int w = lane + (q << 6);
            if (w < NG) S += ps[w];
        }
        float fcnt = (float)cnt;
        #pragma unroll
        for (int off = 32; off; off >>= 1) {
            fcnt += __shfl_down(fcnt, off);
            S    += __shfl_down(S,    off);
        }
        if (lane == 0) {
            s_cnt[mi] = fcnt;
            s_sc[mi]  = cate_scores[i] * (S / fmaxf(fcnt, 1.0f));
        }
    }
    __syncthreads();

    // ---- all within-class pairs: one wave per pair, rows L2-hot (<=120 KB/class)
    const int npairs = m * (m - 1) / 2;
    for (int p = wav; p < npairs; p += 16) {
        int mj = 1;                                    // largest mj with mj(mj-1)/2 <= p
        while ((mj * (mj + 1)) / 2 <= p) ++mj;         // wave-uniform, m small
        const int mi = p - mj * (mj - 1) / 2;
        const int i = s_list[mi], j = s_list[mj];
        const ulonglong2* __restrict__ pi2 = (const ulonglong2*)(packed_d + (size_t)i * DSTR);
        const ulonglong2* __restrict__ pj2 = (const ulonglong2*)(packed_d + (size_t)j * DSTR);
        int inter = 0;
        #pragma unroll
        for (int q = 0; q < 8; ++q) {
            const int w = lane + (q << 6);
            if (w < NW2) {
                const ulonglong2 a = pi2[w];
                const ulonglong2 b = pj2[w];
                inter += __popcll(a.x & b.x) + __popcll(a.y & b.y);
            }
        }
        float fint = (float)inter;
        #pragma unroll
        for (int off = 32; off; off >>= 1) fint += __shfl_down(fint, off);
        if (lane == 0) {
            const float uni = s_cnt[mi] + s_cnt[mj] - fint;
            pm[mi * MM + mj] = fint / fmaxf(uni, 1e-6f);   // iou
        }
    }
    __syncthreads();

    // ---- comp^2 then decay + output: single wave, lane = member index
    if (wav == 0 && lane < m) {
        const int mj = lane;
        float cmax = 0.0f;
        for (int mi = 0; mi < mj; ++mi) cmax = fmaxf(cmax, pm[mi * MM + mj]);
        s_comp[mj] = cmax * cmax;
    }
    __syncthreads();
    if (wav == 0 && lane < m) {
        const int mj = lane;
        float e = 0.0f;                                // min(0, ...) — clamp at coef 1
        for (int mi = 0; mi < mj; ++mi) {
            const float d = pm[mi * MM + mj];
            e = fminf(e, s_comp[mi] - d * d);
        }
        out[s_list[mj]] = s_sc[mj] * expf(SIGMA * e);
    }
}

extern "C" void kernel_launch(void* const* d_in, const int* in_sizes, int n_in,
                              void* d_out, int out_size, void* d_ws, size_t ws_size,
                              hipStream_t stream) {
    const float* cate_scores = (const float*)d_in[0];
    const float* seg_x       = (const float*)d_in[1];
    const float* seg_y       = (const float*)d_in[2];
    const int*   labels      = (const int*)d_in[3];
    const int*   x_inds      = (const int*)d_in[4];
    const int*   y_inds      = (const int*)d_in[5];
    float* out = (float*)d_out;

    // workspace layout (16B-aligned); total ~4.3 MB
    char* ws = (char*)d_ws;
    unsigned long long* packed_d = (unsigned long long*)(ws + 0);   // 500*952*8 = 3,808,000
    float* part4 = (float*)(ws + 3808000);                          // 500*240*4 =   480,000

    maskgen_kernel  <<<NG,   512,  0, stream>>>(seg_x, seg_y, x_inds, y_inds,
                                                packed_d, part4);
    class_nms_kernel<<<NCLS, 1024, 0, stream>>>(packed_d, part4, labels,
                                                cate_scores, out);
}

// Round 3
// 125.821 us; speedup vs baseline: 1.0558x; 1.0364x over previous
//
#include <hip/hip_runtime.h>

// DecoupledSOLOHead: SOLO mask decode + Matrix NMS (gaussian), MI355X/gfx950.
//
// R11 vs R10 (130.4 us): restore maskgen CU overlap lost in R10.
//  - R10's GRP=4 -> 238 blocks @ 64KB LDS = 1 block/CU: stage->gather
//    serialization with nothing co-resident to overlap. GRP=2 -> 475 blocks
//    = 2 blocks/CU (LDS-limited), one block streams HBM while the other
//    gathers. 950 = 475*2 exact, so no tail guard.
//  - Det-major direct write kept: chunk = 2 words = 16B; DSTR=950 -> row
//    stride 7600B, chunk at d*950+g*2 is 16B-aligned. No padding.
//  - part sums: part2[500][475] (stride 480), read coalesced in class_nms.
//  - class_nms unchanged from R10 (passed, absmax 0).

#define N_DET 500
#define HW    (200 * 304)        // 60800
#define TILE  64
#define NT    (HW / TILE)        // 950 tiles, exact
#define GRP   2                  // tiles per maskgen block
#define NG    475                // 950/2, exact
#define DSTR  950                // det-major row stride (words; 7600B, 16B-aligned chunks)
#define NW2   (DSTR / 2)         // 475 ulonglong2 granules per det row
#define PS_STR 480               // part2 row stride (floats); slots [475,480) never read
#define NCLS  80
#define MM    64                 // max members/class (binomial(500,1/80): ~6 avg, ~15 max)
#define MASK_THR 0.005f
#define SIGMA 2.0f

// ---- Kernel A: 2-tile broadcast decode + bit-pack, det-major direct ----------
__global__ __launch_bounds__(512) void maskgen_kernel(
    const float* __restrict__ seg_x, const float* __restrict__ seg_y,
    const int* __restrict__ x_inds, const int* __restrict__ y_inds,
    unsigned long long* __restrict__ packed_d,  // [N_DET][DSTR]
    float* __restrict__ part2)                  // [N_DET][PS_STR]
{
    __shared__ __align__(16) float sx[128 * 64];     // 32,768 B
    __shared__ __align__(16) float sy[128 * 64];     // 32,768 B  (64KB total -> 2 blocks/CU)
    const int g   = blockIdx.x;
    const int tid = threadIdx.x;

    int xrow = 0, yrow = 0;
    if (tid < N_DET) { xrow = x_inds[tid] << 6; yrow = y_inds[tid] << 6; }

    unsigned long long wacc[GRP];
    float ssum = 0.0f;

    #pragma unroll
    for (int u = 0; u < GRP; ++u) {
        const int t = g * GRP + u;                   // < 950 always (exact split)
        const int base = t * TILE;
        __syncthreads();                             // LDS reuse guard (u>0)
        for (int e = tid; e < 128 * 16; e += 512) {
            const int r  = e >> 4;
            const int c4 = (e & 15) << 2;
            *(float4*)(sx + (r << 6) + c4) = *(const float4*)(seg_x + (size_t)r * HW + base + c4);
            *(float4*)(sy + (r << 6) + c4) = *(const float4*)(seg_y + (size_t)r * HW + base + c4);
        }
        __syncthreads();
        unsigned long long w = 0ull;
        if (tid < N_DET) {
            const float4* __restrict__ rx4 = (const float4*)(sx + xrow);
            const float4* __restrict__ ry4 = (const float4*)(sy + yrow);
            #pragma unroll
            for (int k = 0; k < 16; ++k) {
                const int f = (k + tid) & 15;        // 8 lanes per bank-quad
                const float4 xv = rx4[f];
                const float4 yv = ry4[f];
                const float p0 = xv.x * yv.x, p1 = xv.y * yv.y,
                            p2 = xv.z * yv.z, p3 = xv.w * yv.w;
                const int b0 = p0 > MASK_THR, b1 = p1 > MASK_THR,
                          b2 = p2 > MASK_THR, b3 = p3 > MASK_THR;
                ssum += (b0 ? p0 : 0.0f) + (b1 ? p1 : 0.0f)
                      + (b2 ? p2 : 0.0f) + (b3 ? p3 : 0.0f);
                const unsigned int nib = (unsigned)(b0 | (b1 << 1) | (b2 << 2) | (b3 << 3));
                w |= (unsigned long long)nib << (f << 2);  // pixel-order bits
            }
        }
        wacc[u] = w;
    }

    if (tid < N_DET) {
        unsigned long long* dst = packed_d + (size_t)tid * DSTR + g * GRP;
        ulonglong2 v; v.x = wacc[0]; v.y = wacc[1];
        *(ulonglong2*)dst = v;                       // 16B-aligned det-major chunk
        part2[(size_t)tid * PS_STR + g] = ssum;
    }
}

// ------- Kernel B: class-local fused NMS (scores + IoU + comp + decay + out) ---
__global__ __launch_bounds__(1024) void class_nms_kernel(
    const unsigned long long* __restrict__ packed_d,   // [N_DET][DSTR]
    const float* __restrict__ part2,                   // [N_DET][PS_STR]
    const int* __restrict__ labels,
    const float* __restrict__ cate_scores,
    float* __restrict__ out)                           // [N_DET]
{
    const int c    = blockIdx.x;                       // class id, 0..79
    const int tid  = threadIdx.x;
    const int lane = tid & 63, wav = tid >> 6;         // 16 waves

    __shared__ int   s_list[MM];                       // member det indices, ascending
    __shared__ int   s_wcnt[16];
    __shared__ float s_cnt[MM];                        // mask areas
    __shared__ float s_sc[MM];                         // cate * seg_score
    __shared__ float s_comp[MM];                       // comp_iou^2
    __shared__ float pm[MM * MM];                      // iou[mi][mj], mi<mj (16 KB)
    __shared__ int   s_m;

    // ---- ordered member discovery: ballot compaction (waves cover ascending idx)
    int flag = 0;
    if (tid < N_DET) flag = (labels[tid] == c);
    const unsigned long long bmask = __ballot(flag);
    if (lane == 0) s_wcnt[wav] = __popcll(bmask);
    __syncthreads();
    int pre = 0;
    for (int w2 = 0; w2 < wav; ++w2) pre += s_wcnt[w2];
    if (flag) {
        const int pos = pre + __popcll(bmask & ((1ull << lane) - 1ull));
        if (pos < MM) s_list[pos] = tid;
    }
    if (tid == 0) {
        int mm = 0;
        for (int w2 = 0; w2 < 16; ++w2) mm += s_wcnt[w2];
        s_m = (mm > MM) ? MM : mm;
    }
    __syncthreads();
    const int m = s_m;
    if (m == 0) return;                                // uniform exit

    // ---- per-member area + rescored score: one wave per member, coalesced rows
    for (int mi = wav; mi < m; mi += 16) {
        const int i = s_list[mi];
        const ulonglong2* __restrict__ pi2 = (const ulonglong2*)(packed_d + (size_t)i * DSTR);
        const float*      __restrict__ ps  = part2 + (size_t)i * PS_STR;
        int cnt = 0;
        #pragma unroll
        for (int q = 0; q < 8; ++q) {
            const int w = lane + (q << 6);
            if (w < NW2) {
                const ulonglong2 a = pi2[w];
                cnt += __popcll(a.x) + __popcll(a.y);
            }
        }
        float S = 0.0f;
        #pragma unroll
        for (int q = 0; q < 8; ++q) {
            const int w = lane + (q << 6);
            if (w < NG) S += ps[w];
        }
        float fcnt = (float)cnt;
        #pragma unroll
        for (int off = 32; off; off >>= 1) {
            fcnt += __shfl_down(fcnt, off);
            S    += __shfl_down(S,    off);
        }
        if (lane == 0) {
            s_cnt[mi] = fcnt;
            s_sc[mi]  = cate_scores[i] * (S / fmaxf(fcnt, 1.0f));
        }
    }
    __syncthreads();

    // ---- all within-class pairs: one wave per pair, rows L2-hot (<=120 KB/class)
    const int npairs = m * (m - 1) / 2;
    for (int p = wav; p < npairs; p += 16) {
        int mj = 1;                                    // largest mj with mj(mj-1)/2 <= p
        while ((mj * (mj + 1)) / 2 <= p) ++mj;         // wave-uniform, m small
        const int mi = p - mj * (mj - 1) / 2;
        const int i = s_list[mi], j = s_list[mj];
        const ulonglong2* __restrict__ pi2 = (const ulonglong2*)(packed_d + (size_t)i * DSTR);
        const ulonglong2* __restrict__ pj2 = (const ulonglong2*)(packed_d + (size_t)j * DSTR);
        int inter = 0;
        #pragma unroll
        for (int q = 0; q < 8; ++q) {
            const int w = lane + (q << 6);
            if (w < NW2) {
                const ulonglong2 a = pi2[w];
                const ulonglong2 b = pj2[w];
                inter += __popcll(a.x & b.x) + __popcll(a.y & b.y);
            }
        }
        float fint = (float)inter;
        #pragma unroll
        for (int off = 32; off; off >>= 1) fint += __shfl_down(fint, off);
        if (lane == 0) {
            const float uni = s_cnt[mi] + s_cnt[mj] - fint;
            pm[mi * MM + mj] = fint / fmaxf(uni, 1e-6f);   // iou
        }
    }
    __syncthreads();

    // ---- comp^2 then decay + output: single wave, lane = member index
    if (wav == 0 && lane < m) {
        const int mj = lane;
        float cmax = 0.0f;
        for (int mi = 0; mi < mj; ++mi) cmax = fmaxf(cmax, pm[mi * MM + mj]);
        s_comp[mj] = cmax * cmax;
    }
    __syncthreads();
    if (wav == 0 && lane < m) {
        const int mj = lane;
        float e = 0.0f;                                // min(0, ...) — clamp at coef 1
        for (int mi = 0; mi < mj; ++mi) {
            const float d = pm[mi * MM + mj];
            e = fminf(e, s_comp[mi] - d * d);
        }
        out[s_list[mj]] = s_sc[mj] * expf(SIGMA * e);
    }
}

extern "C" void kernel_launch(void* const* d_in, const int* in_sizes, int n_in,
                              void* d_out, int out_size, void* d_ws, size_t ws_size,
                              hipStream_t stream) {
    const float* cate_scores = (const float*)d_in[0];
    const float* seg_x       = (const float*)d_in[1];
    const float* seg_y       = (const float*)d_in[2];
    const int*   labels      = (const int*)d_in[3];
    const int*   x_inds      = (const int*)d_in[4];
    const int*   y_inds      = (const int*)d_in[5];
    float* out = (float*)d_out;

    // workspace layout (16B-aligned); total ~4.76 MB
    char* ws = (char*)d_ws;
    unsigned long long* packed_d = (unsigned long long*)(ws + 0);   // 500*950*8 = 3,800,000
    float* part2 = (float*)(ws + 3800000);                          // 500*480*4 =   960,000

    maskgen_kernel  <<<NG,   512,  0, stream>>>(seg_x, seg_y, x_inds, y_inds,
                                                packed_d, part2);
    class_nms_kernel<<<NCLS, 1024, 0, stream>>>(packed_d, part2, labels,
                                                cate_scores, out);
}